// Round 6
// baseline (58.556 us; speedup 1.0000x reference)
//
#include <hip/hip_runtime.h>

// Volume rendering (NeRF-style) for sorted ray_id segments.
// Outputs concatenated in d_out (f32):
//   pred_rgb (R,3) | pred_depth (R,1) | bg_transmittance (R,1) | weight (N,1)

#define RPW 4  // rays per wave; each ray processed in 128-sample passes (2/lane)

struct F2 { float x, y; };          // natural align 4 -> legal at any float*
struct F6 { float v[6]; };          // rgb of two consecutive samples

// ---- DPP helpers (VALU cross-lane, no LDS) ----
template <int CTRL, int ROW_MASK>
__device__ __forceinline__ float dpp_add(float x) {
    int t = __builtin_amdgcn_update_dpp(0, __float_as_int(x), CTRL, ROW_MASK, 0xf, true);
    return x + __int_as_float(t);
}

// wave64 inclusive prefix sum (6 VALU ops); lane 63 holds the total
__device__ __forceinline__ float wave_incl_scan(float x) {
    x = dpp_add<0x111, 0xf>(x);  // row_shr:1
    x = dpp_add<0x112, 0xf>(x);  // row_shr:2
    x = dpp_add<0x114, 0xf>(x);  // row_shr:4
    x = dpp_add<0x118, 0xf>(x);  // row_shr:8
    x = dpp_add<0x142, 0xa>(x);  // row_bcast:15 -> rows 1,3
    x = dpp_add<0x143, 0xc>(x);  // row_bcast:31 -> rows 2,3
    return x;
}

__device__ __forceinline__ float readlane_f32(float x, int lane) {
    return __int_as_float(__builtin_amdgcn_readlane(__float_as_int(x), lane));
}

__global__ void compute_starts_kernel(const int* __restrict__ ray_id,
                                      int n_samples, int n_rays,
                                      int* __restrict__ starts) {
    const int t = blockIdx.x * blockDim.x + threadIdx.x;
    const int stride = gridDim.x * blockDim.x;
    if (t == 0) {
        const int first = ray_id[0];
        for (int r = 0; r <= first; ++r) starts[r] = 0;
        const int last = ray_id[n_samples - 1];
        for (int r = last + 1; r <= n_rays; ++r) starts[r] = n_samples;
    }
    for (int g = t; g * 4 < n_samples; g += stride) {
        const int i4 = g * 4;
        const int4 v = *reinterpret_cast<const int4*>(ray_id + i4);
        const int prev = (i4 == 0) ? v.x : ray_id[i4 - 1];
        const int vals[5] = {prev, v.x, v.y, v.z, v.w};
        #pragma unroll
        for (int j = 0; j < 4; ++j) {
            const int p = vals[j], c = vals[j + 1];
            if (c != p) {
                for (int r = p + 1; r <= c; ++r) starts[r] = i4 + j;
            }
        }
    }
}

struct Slab { F2 sg, zv, dtv; F6 c; };

__device__ __forceinline__ Slab load_slab(const float* __restrict__ sigma_in,
                                          const float* __restrict__ z_in,
                                          const float* __restrict__ dt_in,
                                          const float* __restrict__ rgb,
                                          int base, int lane, int n_samples)
{
    Slab r;
    const int i0 = base + 2 * lane;
    const int il = min(i0, n_samples - 2);
    r.sg  = *reinterpret_cast<const F2*>(sigma_in + il);
    r.zv  = *reinterpret_cast<const F2*>(z_in + il);
    r.dtv = *reinterpret_cast<const F2*>(dt_in + il);
    r.c   = *reinterpret_cast<const F6*>(rgb + 3 * (size_t)il);
    if (i0 > n_samples - 2) {  // clamped: element i0 (== n-1 if active) is in the .y slot
        r.sg.x = r.sg.y; r.zv.x = r.zv.y; r.dtv.x = r.dtv.y;
        r.c.v[0] = r.c.v[3]; r.c.v[1] = r.c.v[4]; r.c.v[2] = r.c.v[5];
    }
    return r;
}

// One 128-sample pass (2 elems/lane). Single-exp formulation:
//   t_i = csum + scan(sigdt); v_i = exp(-t_i); w_i = v_{i-1} - v_i
// carry = exp(-csum) (running transmittance), injected via DPP old operand.
__device__ __forceinline__ void process_pass128(
    const Slab& d, int base, int s1, int lane, int use_exit, float texit,
    float& csum, float& carry,
    float& accR, float& accG, float& accB, float& accD,
    float* __restrict__ out_w)
{
    const int i0 = base + 2 * lane;
    const int i1 = i0 + 1;
    float dt0 = d.dtv.x, dt1v = d.dtv.y;
    if (use_exit && i0 == s1 - 1) dt0  = texit - d.zv.x;
    if (use_exit && i1 == s1 - 1) dt1v = texit - d.zv.y;
    const float e0 = (i0 < s1) ? d.sg.x * dt0  : 0.f;
    const float e1 = (i1 < s1) ? d.sg.y * dt1v : 0.f;

    const float S  = wave_incl_scan(e0 + e1);   // inclusive through this lane's pair
    const float t1 = csum + S;
    const float t0 = t1 - e1;
    const float v0 = __expf(-t0);
    const float v1 = __expf(-t1);
    const int vpi = __builtin_amdgcn_update_dpp(__float_as_int(carry), __float_as_int(v1),
                                                0x138 /*wave_shr:1*/, 0xf, 0xf, false);
    const float vp = __int_as_float(vpi);       // v at end of previous pair (carry for lane 0)
    const float w0 = vp - v0;
    const float w1 = v0 - v1;

    if (i0 < s1) out_w[i0] = w0;
    if (i1 < s1) out_w[i1] = w1;
    accR += w0 * d.c.v[0] + w1 * d.c.v[3];
    accG += w0 * d.c.v[1] + w1 * d.c.v[4];
    accB += w0 * d.c.v[2] + w1 * d.c.v[5];
    accD += w0 * d.zv.x   + w1 * d.zv.y;
    csum  = readlane_f32(t1, 63);
    carry = readlane_f32(v1, 63);
}

__global__ __launch_bounds__(256) void render_kernel(
    const float* __restrict__ rgb,       // (N,3)
    const float* __restrict__ sigma_in,  // (N,1)
    const float* __restrict__ z_in,      // (N,)
    const float* __restrict__ dt_in,     // (N,)
    const float* __restrict__ t_exit,    // (R,1)
    const int*  __restrict__ use_exit_p, // scalar
    const int*  __restrict__ starts,     // (R+1,)
    float* __restrict__ out_rgb,         // (R,3)
    float* __restrict__ out_depth,       // (R,)
    float* __restrict__ out_bg,          // (R,)
    float* __restrict__ out_w,           // (N,)
    int n_rays, int n_samples)
{
    const int wave = threadIdx.x >> 6;
    const int lane = threadIdx.x & 63;
    const int wid  = blockIdx.x * (blockDim.x >> 6) + wave;
    const int ray0 = wid * RPW;
    if (ray0 >= n_rays) return;

    const int use_exit = *use_exit_p;

    // ---- boundaries -> SGPRs (uniform) ----
    int s[RPW + 1];
    #pragma unroll
    for (int k = 0; k <= RPW; ++k) {
        s[k] = __builtin_amdgcn_readfirstlane(starts[min(ray0 + k, n_rays)]);
    }
    float texit[RPW];
    #pragma unroll
    for (int k = 0; k < RPW; ++k) {
        texit[k] = readlane_f32(t_exit[min(ray0 + k, n_rays - 1)], 0);
    }

    // ---- pass-1 slabs for all rays: issue every load, then PIN with asm ----
    Slab sl[RPW];
    #pragma unroll
    for (int k = 0; k < RPW; ++k) {
        sl[k] = load_slab(sigma_in, z_in, dt_in, rgb, s[k], lane, n_samples);
    }
    #pragma unroll
    for (int k = 0; k < RPW; ++k) {
        asm volatile("" ::
            "v"(sl[k].sg.x), "v"(sl[k].sg.y), "v"(sl[k].zv.x), "v"(sl[k].zv.y),
            "v"(sl[k].dtv.x), "v"(sl[k].dtv.y),
            "v"(sl[k].c.v[0]), "v"(sl[k].c.v[1]), "v"(sl[k].c.v[2]),
            "v"(sl[k].c.v[3]), "v"(sl[k].c.v[4]), "v"(sl[k].c.v[5]));
    }
    __builtin_amdgcn_sched_barrier(0);

    // ---- process rays from registers ----
    #pragma unroll
    for (int k = 0; k < RPW; ++k) {
        const int ray = ray0 + k;
        if (ray >= n_rays) break;
        const int s0 = s[k], s1 = s[k + 1];
        float csum = 0.f, carry = 1.0f;
        float accR = 0.f, accG = 0.f, accB = 0.f, accD = 0.f;

        process_pass128(sl[k], s0, s1, lane, use_exit, texit[k],
                        csum, carry, accR, accG, accB, accD, out_w);

        // rare: rays longer than 128 samples (~8-sigma; correctness only)
        for (int base = s0 + 128; base < s1; base += 128) {
            const Slab d = load_slab(sigma_in, z_in, dt_in, rgb, base, lane, n_samples);
            process_pass128(d, base, s1, lane, use_exit, texit[k],
                            csum, carry, accR, accG, accB, accD, out_w);
        }

        // per-ray reduction: inclusive scan, lane 63 holds totals
        accR = wave_incl_scan(accR);
        accG = wave_incl_scan(accG);
        accB = wave_incl_scan(accB);
        accD = wave_incl_scan(accD);
        if (lane == 63) {
            out_rgb[3 * ray + 0] = accR;
            out_rgb[3 * ray + 1] = accB == accB ? accG : accG; // keep simple; see below
            out_rgb[3 * ray + 1] = accG;
            out_rgb[3 * ray + 2] = accB;
            out_depth[ray] = accD;
            out_bg[ray]    = carry;   // exp(-total sigdt)
        }
    }
}

extern "C" void kernel_launch(void* const* d_in, const int* in_sizes, int n_in,
                              void* d_out, int out_size, void* d_ws, size_t ws_size,
                              hipStream_t stream) {
    const float* rgb     = (const float*)d_in[0];
    const float* sigma   = (const float*)d_in[1];
    const float* z       = (const float*)d_in[2];
    const float* dt      = (const float*)d_in[3];
    const int*   ray_id  = (const int*)d_in[4];
    const float* t_exit  = (const float*)d_in[5];
    const int*   use_ex  = (const int*)d_in[6];

    const int n_samples = in_sizes[2];   // samples_z flat count
    const int n_rays    = in_sizes[5];   // ray_t_exit flat count

    int* starts = (int*)d_ws;            // (n_rays + 1) ints

    float* out      = (float*)d_out;
    float* out_rgb  = out;
    float* out_dep  = out + (size_t)3 * n_rays;
    float* out_bg   = out + (size_t)4 * n_rays;
    float* out_w    = out + (size_t)5 * n_rays;

    compute_starts_kernel<<<2048, 256, 0, stream>>>(ray_id, n_samples, n_rays, starts);

    const int waves_per_block = 4;              // 256 threads
    const int rays_per_block  = waves_per_block * RPW;
    const int blocks = (n_rays + rays_per_block - 1) / rays_per_block;
    render_kernel<<<blocks, 256, 0, stream>>>(rgb, sigma, z, dt, t_exit, use_ex,
                                              starts, out_rgb, out_dep, out_bg,
                                              out_w, n_rays, n_samples);
}

// Round 8
// 58.488 us; speedup vs baseline: 1.0012x; 1.0012x over previous
//
#include <hip/hip_runtime.h>

// Volume rendering (NeRF-style) for sorted ray_id segments.
// Outputs concatenated in d_out (f32):
//   pred_rgb (R,3) | pred_depth (R,1) | bg_transmittance (R,1) | weight (N,1)

#define RPW 4  // rays per wave; each ray handled in one 128-sample pass (2/lane)

struct F2 { float x, y; };          // align 4 -> legal at any float*
struct F6 { float v[6]; };          // rgb of two consecutive samples

// ---- DPP helpers (VALU cross-lane, no LDS) ----
template <int CTRL, int ROW_MASK>
__device__ __forceinline__ float dpp_add(float x) {
    int t = __builtin_amdgcn_update_dpp(0, __float_as_int(x), CTRL, ROW_MASK, 0xf, true);
    return x + __int_as_float(t);
}

// wave64 inclusive prefix sum (6 VALU ops); lane 63 holds the total
__device__ __forceinline__ float wave_incl_scan(float x) {
    x = dpp_add<0x111, 0xf>(x);  // row_shr:1
    x = dpp_add<0x112, 0xf>(x);  // row_shr:2
    x = dpp_add<0x114, 0xf>(x);  // row_shr:4
    x = dpp_add<0x118, 0xf>(x);  // row_shr:8
    x = dpp_add<0x142, 0xa>(x);  // row_bcast:15 -> rows 1,3
    x = dpp_add<0x143, 0xc>(x);  // row_bcast:31 -> rows 2,3
    return x;
}

__device__ __forceinline__ float readlane_f32(float x, int lane) {
    return __int_as_float(__builtin_amdgcn_readlane(__float_as_int(x), lane));
}

__global__ void compute_starts_kernel(const int* __restrict__ ray_id,
                                      int n_samples, int n_rays,
                                      int* __restrict__ starts) {
    const int t = blockIdx.x * blockDim.x + threadIdx.x;
    const int stride = gridDim.x * blockDim.x;
    if (t == 0) {
        const int first = ray_id[0];
        for (int r = 0; r <= first; ++r) starts[r] = 0;
        const int last = ray_id[n_samples - 1];
        for (int r = last + 1; r <= n_rays; ++r) starts[r] = n_samples;
    }
    for (int g = t; g * 4 < n_samples; g += stride) {
        const int i4 = g * 4;
        const int4 v = *reinterpret_cast<const int4*>(ray_id + i4);
        const int prev = (i4 == 0) ? v.x : ray_id[i4 - 1];
        const int vals[5] = {prev, v.x, v.y, v.z, v.w};
        #pragma unroll
        for (int j = 0; j < 4; ++j) {
            const int p = vals[j], c = vals[j + 1];
            if (c != p) {
                for (int r = p + 1; r <= c; ++r) starts[r] = i4 + j;
            }
        }
    }
}

struct Slab { F2 sg, zv, dtv; F6 c; };

__device__ __forceinline__ Slab load_slab(const float* __restrict__ sigma_in,
                                          const float* __restrict__ z_in,
                                          const float* __restrict__ dt_in,
                                          const float* __restrict__ rgb,
                                          int base, int lane, int n_samples)
{
    Slab r;
    const int i0 = base + 2 * lane;
    const int il = min(i0, n_samples - 2);
    r.sg  = *reinterpret_cast<const F2*>(sigma_in + il);
    r.zv  = *reinterpret_cast<const F2*>(z_in + il);
    r.dtv = *reinterpret_cast<const F2*>(dt_in + il);
    r.c   = *reinterpret_cast<const F6*>(rgb + 3 * (size_t)il);
    if (i0 > n_samples - 2) {  // clamped: sample i0 (== n-1 if active) is in the .y slot
        r.sg.x = r.sg.y; r.zv.x = r.zv.y; r.dtv.x = r.dtv.y;
        r.c.v[0] = r.c.v[3]; r.c.v[1] = r.c.v[4]; r.c.v[2] = r.c.v[5];
    }
    return r;
}

// rare-path (rays > 128 samples): one 128-sample pass with running carry
__device__ __forceinline__ void process_pass128_rare(
    const Slab& d, int base, int s1, int lane, int use_exit, float texit,
    float& csum, float& carry,
    float& aR, float& aG, float& aB, float& aD,
    float* __restrict__ out_w)
{
    const int i0 = base + 2 * lane, i1 = i0 + 1;
    float dt0 = d.dtv.x, dt1 = d.dtv.y;
    if (use_exit && i0 == s1 - 1) dt0 = texit - d.zv.x;
    if (use_exit && i1 == s1 - 1) dt1 = texit - d.zv.y;
    const float e0 = (i0 < s1) ? d.sg.x * dt0 : 0.f;
    const float e1 = (i1 < s1) ? d.sg.y * dt1 : 0.f;
    const float t1 = csum + wave_incl_scan(e0 + e1);
    const float v0 = __expf(-(t1 - e1));
    const float v1 = __expf(-t1);
    const int vpi = __builtin_amdgcn_update_dpp(__float_as_int(carry), __float_as_int(v1),
                                                0x138 /*wave_shr:1*/, 0xf, 0xf, false);
    const float w0 = __int_as_float(vpi) - v0;
    const float w1 = v0 - v1;
    if (i0 < s1) out_w[i0] = w0;
    if (i1 < s1) out_w[i1] = w1;
    aR += w0 * d.c.v[0] + w1 * d.c.v[3];
    aG += w0 * d.c.v[1] + w1 * d.c.v[4];
    aB += w0 * d.c.v[2] + w1 * d.c.v[5];
    aD += w0 * d.zv.x + w1 * d.zv.y;
    csum  = readlane_f32(t1, 63);
    carry = readlane_f32(v1, 63);
}

__global__ __launch_bounds__(256) void render_kernel(
    const float* __restrict__ rgb,       // (N,3)
    const float* __restrict__ sigma_in,  // (N,1)
    const float* __restrict__ z_in,      // (N,)
    const float* __restrict__ dt_in,     // (N,)
    const float* __restrict__ t_exit,    // (R,1)
    const int*  __restrict__ use_exit_p, // scalar
    const int*  __restrict__ starts,     // (R+1,)
    float* __restrict__ out_rgb,         // (R,3)
    float* __restrict__ out_depth,       // (R,)
    float* __restrict__ out_bg,          // (R,)
    float* __restrict__ out_w,           // (N,)
    int n_rays, int n_samples)
{
    const int wave = threadIdx.x >> 6;
    const int lane = threadIdx.x & 63;
    const int wid  = blockIdx.x * (blockDim.x >> 6) + wave;
    const int ray0 = wid * RPW;

    const int use_exit = *use_exit_p;

    // ---- boundaries -> SGPRs (uniform; min() clamps, no branches) ----
    int s[RPW + 1];
    #pragma unroll
    for (int k = 0; k <= RPW; ++k) {
        s[k] = __builtin_amdgcn_readfirstlane(starts[min(ray0 + k, n_rays)]);
    }
    float tex[RPW];
    #pragma unroll
    for (int k = 0; k < RPW; ++k) {
        tex[k] = readlane_f32(t_exit[min(ray0 + k, n_rays - 1)], 0);
    }

    // ---- ALL data loads, single basic block ----
    Slab sl[RPW];
    #pragma unroll
    for (int k = 0; k < RPW; ++k) {
        sl[k] = load_slab(sigma_in, z_in, dt_in, rgb, s[k], lane, n_samples);
    }
    __builtin_amdgcn_sched_barrier(0);  // loads above, compute below (same BB)

    // ---- pure-VALU compute for all rays (no stores -> no BB splits) ----
    float accR[RPW], accG[RPW], accB[RPW], accD[RPW];
    float w0v[RPW], w1v[RPW], t1v[RPW], v1v[RPW];
    #pragma unroll
    for (int k = 0; k < RPW; ++k) {
        const int s1 = s[k + 1];
        const int i0 = s[k] + 2 * lane;
        const int i1 = i0 + 1;
        float dt0 = sl[k].dtv.x, dt1 = sl[k].dtv.y;
        if (use_exit && i0 == s1 - 1) dt0 = tex[k] - sl[k].zv.x;
        if (use_exit && i1 == s1 - 1) dt1 = tex[k] - sl[k].zv.y;
        const float e0 = (i0 < s1) ? sl[k].sg.x * dt0 : 0.f;
        const float e1 = (i1 < s1) ? sl[k].sg.y * dt1 : 0.f;
        const float t1 = wave_incl_scan(e0 + e1);   // csum = 0 on pass 1
        const float v0 = __expf(-(t1 - e1));
        const float v1 = __expf(-t1);
        const int vpi = __builtin_amdgcn_update_dpp(0x3f800000 /*1.0f*/, __float_as_int(v1),
                                                    0x138 /*wave_shr:1*/, 0xf, 0xf, false);
        const float vp = __int_as_float(vpi);
        const float w0 = vp - v0;
        const float w1 = v0 - v1;
        w0v[k] = w0;  w1v[k] = w1;
        accR[k] = w0 * sl[k].c.v[0] + w1 * sl[k].c.v[3];
        accG[k] = w0 * sl[k].c.v[1] + w1 * sl[k].c.v[4];
        accB[k] = w0 * sl[k].c.v[2] + w1 * sl[k].c.v[5];
        accD[k] = w0 * sl[k].zv.x   + w1 * sl[k].zv.y;
        t1v[k] = t1;  v1v[k] = v1;
    }

    // ---- rare continuation for rays > 128 samples (wave-uniform, ~never) ----
    bool anylong = false;
    #pragma unroll
    for (int k = 0; k < RPW; ++k) anylong |= (s[k] + 128 < s[k + 1]);
    if (anylong) {
        #pragma unroll
        for (int k = 0; k < RPW; ++k) {
            float csum  = readlane_f32(t1v[k], 63);
            float carry = readlane_f32(v1v[k], 63);
            for (int base = s[k] + 128; base < s[k + 1]; base += 128) {
                const Slab d = load_slab(sigma_in, z_in, dt_in, rgb, base, lane, n_samples);
                process_pass128_rare(d, base, s[k + 1], lane, use_exit, tex[k],
                                     csum, carry, accR[k], accG[k], accB[k], accD[k], out_w);
            }
            // make bg uniform-correct for long rays
            v1v[k] = carry;
        }
    }

    // ---- stores: per-sample weights ----
    #pragma unroll
    for (int k = 0; k < RPW; ++k) {
        const int s1 = s[k + 1];
        const int i0 = s[k] + 2 * lane;
        if (i0 < s1)     out_w[i0]     = w0v[k];
        if (i0 + 1 < s1) out_w[i0 + 1] = w1v[k];
    }

    // ---- per-ray reductions + ray outputs ----
    #pragma unroll
    for (int k = 0; k < RPW; ++k) {
        const float r = wave_incl_scan(accR[k]);
        const float g = wave_incl_scan(accG[k]);
        const float b = wave_incl_scan(accB[k]);
        const float d = wave_incl_scan(accD[k]);
        const int ray = ray0 + k;
        if (lane == 63 && ray < n_rays) {
            out_rgb[3 * ray + 0] = r;
            out_rgb[3 * ray + 1] = g;
            out_rgb[3 * ray + 2] = b;
            out_depth[ray] = d;
            out_bg[ray]    = v1v[k];   // exp(-total sigdt)
        }
    }
}

extern "C" void kernel_launch(void* const* d_in, const int* in_sizes, int n_in,
                              void* d_out, int out_size, void* d_ws, size_t ws_size,
                              hipStream_t stream) {
    const float* rgb     = (const float*)d_in[0];
    const float* sigma   = (const float*)d_in[1];
    const float* z       = (const float*)d_in[2];
    const float* dt      = (const float*)d_in[3];
    const int*   ray_id  = (const int*)d_in[4];
    const float* t_exit  = (const float*)d_in[5];
    const int*   use_ex  = (const int*)d_in[6];

    const int n_samples = in_sizes[2];   // samples_z flat count
    const int n_rays    = in_sizes[5];   // ray_t_exit flat count

    int* starts = (int*)d_ws;            // (n_rays + 1) ints

    float* out      = (float*)d_out;
    float* out_rgb  = out;
    float* out_dep  = out + (size_t)3 * n_rays;
    float* out_bg   = out + (size_t)4 * n_rays;
    float* out_w    = out + (size_t)5 * n_rays;

    compute_starts_kernel<<<2048, 256, 0, stream>>>(ray_id, n_samples, n_rays, starts);

    const int waves_per_block = 4;              // 256 threads
    const int rays_per_block  = waves_per_block * RPW;
    const int blocks = (n_rays + rays_per_block - 1) / rays_per_block;
    render_kernel<<<blocks, 256, 0, stream>>>(rgb, sigma, z, dt, t_exit, use_ex,
                                              starts, out_rgb, out_dep, out_bg,
                                              out_w, n_rays, n_samples);
}

// Round 9
// 55.518 us; speedup vs baseline: 1.0547x; 1.0535x over previous
//
#include <hip/hip_runtime.h>

// Volume rendering (NeRF-style) for sorted ray_id segments.
// Outputs concatenated in d_out (f32):
//   pred_rgb (R,3) | pred_depth (R,1) | bg_transmittance (R,1) | weight (N,1)

#define RPW 4  // rays per wave; each ray handled in one 128-sample pass (2/lane)

typedef float __attribute__((ext_vector_type(2))) f32x2;
typedef float __attribute__((ext_vector_type(4))) f32x4;

// ---- forced wide loads: issued immediately, NOT waited (caller drains vmcnt) ----
__device__ __forceinline__ f32x2 async_load2(const float* p) {
    f32x2 r;
    asm volatile("global_load_dwordx2 %0, %1, off" : "=v"(r) : "v"(p));
    return r;
}
__device__ __forceinline__ f32x4 async_load4(const float* p) {
    f32x4 r;
    asm volatile("global_load_dwordx4 %0, %1, off" : "=v"(r) : "v"(p));
    return r;
}

// ---- DPP helpers (VALU cross-lane, no LDS) ----
template <int CTRL, int ROW_MASK>
__device__ __forceinline__ float dpp_add(float x) {
    int t = __builtin_amdgcn_update_dpp(0, __float_as_int(x), CTRL, ROW_MASK, 0xf, true);
    return x + __int_as_float(t);
}

// wave64 inclusive prefix sum (6 VALU ops); lane 63 holds the total
__device__ __forceinline__ float wave_incl_scan(float x) {
    x = dpp_add<0x111, 0xf>(x);  // row_shr:1
    x = dpp_add<0x112, 0xf>(x);  // row_shr:2
    x = dpp_add<0x114, 0xf>(x);  // row_shr:4
    x = dpp_add<0x118, 0xf>(x);  // row_shr:8
    x = dpp_add<0x142, 0xa>(x);  // row_bcast:15 -> rows 1,3
    x = dpp_add<0x143, 0xc>(x);  // row_bcast:31 -> rows 2,3
    return x;
}

__device__ __forceinline__ float readlane_f32(float x, int lane) {
    return __int_as_float(__builtin_amdgcn_readlane(__float_as_int(x), lane));
}

__global__ void compute_starts_kernel(const int* __restrict__ ray_id,
                                      int n_samples, int n_rays,
                                      int* __restrict__ starts) {
    const int t = blockIdx.x * blockDim.x + threadIdx.x;
    const int stride = gridDim.x * blockDim.x;
    if (t == 0) {
        const int first = ray_id[0];
        for (int r = 0; r <= first; ++r) starts[r] = 0;
        const int last = ray_id[n_samples - 1];
        for (int r = last + 1; r <= n_rays; ++r) starts[r] = n_samples;
    }
    for (int g = t; g * 4 < n_samples; g += stride) {
        const int i4 = g * 4;
        const int4 v = *reinterpret_cast<const int4*>(ray_id + i4);
        const int prev = (i4 == 0) ? v.x : ray_id[i4 - 1];
        const int vals[5] = {prev, v.x, v.y, v.z, v.w};
        #pragma unroll
        for (int j = 0; j < 4; ++j) {
            const int p = vals[j], c = vals[j + 1];
            if (c != p) {
                for (int r = p + 1; r <= c; ++r) starts[r] = i4 + j;
            }
        }
    }
}

// rare-path (rays > 128 samples): one 128-sample pass with running carry
__device__ __forceinline__ void process_pass128_rare(
    const float* __restrict__ sigma_in, const float* __restrict__ z_in,
    const float* __restrict__ dt_in, const float* __restrict__ rgb,
    int base, int s1, int lane, int use_exit, float texit, int n_samples,
    float& csum, float& carry,
    float& aR, float& aG, float& aB, float& aD,
    float* __restrict__ out_w)
{
    const int i0 = base + 2 * lane, i1 = i0 + 1;
    const int il = min(i0, n_samples - 2);
    float sgx = sigma_in[il],     sgy = sigma_in[il + 1];
    float zvx = z_in[il],         zvy = z_in[il + 1];
    float dtx = dt_in[il],        dty = dt_in[il + 1];
    float c0 = rgb[3 * (size_t)il + 0], c1 = rgb[3 * (size_t)il + 1], c2 = rgb[3 * (size_t)il + 2];
    float c3 = rgb[3 * (size_t)il + 3], c4 = rgb[3 * (size_t)il + 4], c5 = rgb[3 * (size_t)il + 5];
    if (i0 > n_samples - 2) {  // clamped: sample i0 is in the .y slot
        sgx = sgy; zvx = zvy; dtx = dty; c0 = c3; c1 = c4; c2 = c5;
    }
    if (use_exit && i0 == s1 - 1) dtx = texit - zvx;
    if (use_exit && i1 == s1 - 1) dty = texit - zvy;
    const float e0 = (i0 < s1) ? sgx * dtx : 0.f;
    const float e1 = (i1 < s1) ? sgy * dty : 0.f;
    const float t1 = csum + wave_incl_scan(e0 + e1);
    const float v0 = __expf(-(t1 - e1));
    const float v1 = __expf(-t1);
    const int vpi = __builtin_amdgcn_update_dpp(__float_as_int(carry), __float_as_int(v1),
                                                0x138 /*wave_shr:1*/, 0xf, 0xf, false);
    const float w0 = __int_as_float(vpi) - v0;
    const float w1 = v0 - v1;
    if (i0 < s1) out_w[i0] = w0;
    if (i1 < s1) out_w[i1] = w1;
    aR += w0 * c0 + w1 * c3;
    aG += w0 * c1 + w1 * c4;
    aB += w0 * c2 + w1 * c5;
    aD += w0 * zvx + w1 * zvy;
    csum  = readlane_f32(t1, 63);
    carry = readlane_f32(v1, 63);
}

__global__ __launch_bounds__(256) void render_kernel(
    const float* __restrict__ rgb,       // (N,3)
    const float* __restrict__ sigma_in,  // (N,1)
    const float* __restrict__ z_in,      // (N,)
    const float* __restrict__ dt_in,     // (N,)
    const float* __restrict__ t_exit,    // (R,1)
    const int*  __restrict__ use_exit_p, // scalar
    const int*  __restrict__ starts,     // (R+1,)
    float* __restrict__ out_rgb,         // (R,3)
    float* __restrict__ out_depth,       // (R,)
    float* __restrict__ out_bg,          // (R,)
    float* __restrict__ out_w,           // (N,)
    int n_rays, int n_samples)
{
    const int wave = threadIdx.x >> 6;
    const int lane = threadIdx.x & 63;
    const int wid  = blockIdx.x * (blockDim.x >> 6) + wave;
    const int ray0 = wid * RPW;

    const int use_exit = *use_exit_p;

    // ---- boundaries -> SGPRs (uniform) ----
    int s[RPW + 1];
    #pragma unroll
    for (int k = 0; k <= RPW; ++k) {
        s[k] = __builtin_amdgcn_readfirstlane(starts[min(ray0 + k, n_rays)]);
    }
    float tex[RPW];
    #pragma unroll
    for (int k = 0; k < RPW; ++k) {
        tex[k] = readlane_f32(t_exit[min(ray0 + k, n_rays - 1)], 0);
    }

    // ---- ALL data loads forced in-flight via asm (20 VMEM ops, one drain) ----
    f32x2 sg[RPW], zv[RPW], dtv[RPW], c45[RPW];
    f32x4 c03[RPW];
    #pragma unroll
    for (int k = 0; k < RPW; ++k) {
        const int i0 = s[k] + 2 * lane;
        const int il = min(i0, n_samples - 2);
        sg[k]  = async_load2(sigma_in + il);
        zv[k]  = async_load2(z_in + il);
        dtv[k] = async_load2(dt_in + il);
        c03[k] = async_load4(rgb + 3 * (size_t)il);
        c45[k] = async_load2(rgb + 3 * (size_t)il + 4);
    }
    asm volatile("s_waitcnt vmcnt(0)" ::: "memory");
    __builtin_amdgcn_sched_barrier(0);   // consumers must not hoist above the drain

    // ---- pure-VALU compute for all rays ----
    float accR[RPW], accG[RPW], accB[RPW], accD[RPW];
    float w0v[RPW], w1v[RPW], t1v[RPW], v1v[RPW];
    #pragma unroll
    for (int k = 0; k < RPW; ++k) {
        const int s1 = s[k + 1];
        const int i0 = s[k] + 2 * lane;
        const int i1 = i0 + 1;
        const bool clamped = i0 > n_samples - 2;   // sample i0 sits in the .y slot
        const float sgx = clamped ? sg[k].y : sg[k].x;
        const float sgy = sg[k].y;
        const float zvx = clamped ? zv[k].y : zv[k].x;
        const float zvy = zv[k].y;
        float dt0 = clamped ? dtv[k].y : dtv[k].x;
        float dt1 = dtv[k].y;
        const float cc0 = clamped ? c03[k].w : c03[k].x;
        const float cc1 = clamped ? c45[k].x : c03[k].y;
        const float cc2 = clamped ? c45[k].y : c03[k].z;
        const float cc3 = c03[k].w;
        const float cc4 = c45[k].x;
        const float cc5 = c45[k].y;
        if (use_exit && i0 == s1 - 1) dt0 = tex[k] - zvx;
        if (use_exit && i1 == s1 - 1) dt1 = tex[k] - zvy;
        const float e0 = (i0 < s1) ? sgx * dt0 : 0.f;
        const float e1 = (i1 < s1) ? sgy * dt1 : 0.f;
        const float t1 = wave_incl_scan(e0 + e1);   // csum = 0 on pass 1
        const float v0 = __expf(-(t1 - e1));
        const float v1 = __expf(-t1);
        const int vpi = __builtin_amdgcn_update_dpp(0x3f800000 /*1.0f*/, __float_as_int(v1),
                                                    0x138 /*wave_shr:1*/, 0xf, 0xf, false);
        const float vp = __int_as_float(vpi);
        const float w0 = vp - v0;
        const float w1 = v0 - v1;
        w0v[k] = w0;  w1v[k] = w1;
        accR[k] = w0 * cc0 + w1 * cc3;
        accG[k] = w0 * cc1 + w1 * cc4;
        accB[k] = w0 * cc2 + w1 * cc5;
        accD[k] = w0 * zvx + w1 * zvy;
        t1v[k] = t1;  v1v[k] = v1;
    }

    // ---- rare continuation for rays > 128 samples (wave-uniform, ~never) ----
    bool anylong = false;
    #pragma unroll
    for (int k = 0; k < RPW; ++k) anylong |= (s[k] + 128 < s[k + 1]);
    if (anylong) {
        #pragma unroll
        for (int k = 0; k < RPW; ++k) {
            float csum  = readlane_f32(t1v[k], 63);
            float carry = readlane_f32(v1v[k], 63);
            for (int base = s[k] + 128; base < s[k + 1]; base += 128) {
                process_pass128_rare(sigma_in, z_in, dt_in, rgb,
                                     base, s[k + 1], lane, use_exit, tex[k], n_samples,
                                     csum, carry, accR[k], accG[k], accB[k], accD[k], out_w);
            }
            v1v[k] = carry;  // bg for long rays
        }
    }

    // ---- stores: per-sample weights ----
    #pragma unroll
    for (int k = 0; k < RPW; ++k) {
        const int s1 = s[k + 1];
        const int i0 = s[k] + 2 * lane;
        if (i0 < s1)     out_w[i0]     = w0v[k];
        if (i0 + 1 < s1) out_w[i0 + 1] = w1v[k];
    }

    // ---- per-ray reductions + ray outputs ----
    #pragma unroll
    for (int k = 0; k < RPW; ++k) {
        const float r = wave_incl_scan(accR[k]);
        const float g = wave_incl_scan(accG[k]);
        const float b = wave_incl_scan(accB[k]);
        const float d = wave_incl_scan(accD[k]);
        const int ray = ray0 + k;
        if (lane == 63 && ray < n_rays) {
            out_rgb[3 * ray + 0] = r;
            out_rgb[3 * ray + 1] = g;
            out_rgb[3 * ray + 2] = b;
            out_depth[ray] = d;
            out_bg[ray]    = v1v[k];   // exp(-total sigdt)
        }
    }
}

extern "C" void kernel_launch(void* const* d_in, const int* in_sizes, int n_in,
                              void* d_out, int out_size, void* d_ws, size_t ws_size,
                              hipStream_t stream) {
    const float* rgb     = (const float*)d_in[0];
    const float* sigma   = (const float*)d_in[1];
    const float* z       = (const float*)d_in[2];
    const float* dt      = (const float*)d_in[3];
    const int*   ray_id  = (const int*)d_in[4];
    const float* t_exit  = (const float*)d_in[5];
    const int*   use_ex  = (const int*)d_in[6];

    const int n_samples = in_sizes[2];   // samples_z flat count
    const int n_rays    = in_sizes[5];   // ray_t_exit flat count

    int* starts = (int*)d_ws;            // (n_rays + 1) ints

    float* out      = (float*)d_out;
    float* out_rgb  = out;
    float* out_dep  = out + (size_t)3 * n_rays;
    float* out_bg   = out + (size_t)4 * n_rays;
    float* out_w    = out + (size_t)5 * n_rays;

    compute_starts_kernel<<<2048, 256, 0, stream>>>(ray_id, n_samples, n_rays, starts);

    const int waves_per_block = 4;              // 256 threads
    const int rays_per_block  = waves_per_block * RPW;
    const int blocks = (n_rays + rays_per_block - 1) / rays_per_block;
    render_kernel<<<blocks, 256, 0, stream>>>(rgb, sigma, z, dt, t_exit, use_ex,
                                              starts, out_rgb, out_dep, out_bg,
                                              out_w, n_rays, n_samples);
}